// Round 2
// baseline (1302.759 us; speedup 1.0000x reference)
//
#include <hip/hip_runtime.h>

#define NODES 10000
#define EDGES 160000
#define INF_ 16
#define DD 512
#define GRAPHS 64
#define NOUT 18
#define BN_EPS 1e-5f

__global__ void k_zero_i32(int* p, int n) { int i = blockIdx.x * 256 + threadIdx.x; if (i < n) p[i] = 0; }
__global__ void k_zero_f32(float* p, int n) { int i = blockIdx.x * 256 + threadIdx.x; if (i < n) p[i] = 0.f; }

// ---- CSR build (dst-indexed): count -> scan -> fill ----
__global__ void k_count(const int* __restrict__ dst, int* __restrict__ cnt) {
  int e = blockIdx.x * 256 + threadIdx.x;
  if (e < EDGES) atomicAdd(&cnt[dst[e]], 1);
}

__global__ __launch_bounds__(1024) void k_scan(const int* __restrict__ cnt, int* __restrict__ rowptr) {
  __shared__ int s[1024];
  int t = threadIdx.x;
  int base = t * 10;
  int c[10]; int sum = 0;
#pragma unroll
  for (int i = 0; i < 10; ++i) { int idx = base + i; c[i] = (idx < NODES) ? cnt[idx] : 0; sum += c[i]; }
  s[t] = sum; __syncthreads();
  for (int off = 1; off < 1024; off <<= 1) {
    int v = s[t];
    int a = (t >= off) ? s[t - off] : 0;
    __syncthreads();
    s[t] = v + a;
    __syncthreads();
  }
  int run = (t == 0) ? 0 : s[t - 1];
#pragma unroll
  for (int i = 0; i < 10; ++i) { int idx = base + i; if (idx < NODES) rowptr[idx] = run; run += c[i]; }
  if (t == 1023) rowptr[NODES] = s[1023];
}

__global__ void k_fill(const int* __restrict__ src, const int* __restrict__ dst,
                       const int* __restrict__ rowptr, int* __restrict__ cur, int* __restrict__ col) {
  int e = blockIdx.x * 256 + threadIdx.x;
  if (e < EDGES) {
    int d = dst[e];
    int p = atomicAdd(&cur[d], 1);
    col[rowptr[d] + p] = src[e];
  }
}

// ---- layer-1 aggregation on [NODES,16] fp32 ----
__global__ void k_agg16(const float* __restrict__ x, const int* __restrict__ rowptr,
                        const int* __restrict__ col, float* __restrict__ h0) {
  int t = threadIdx.x;
  int node = blockIdx.x * 16 + (t >> 4);
  int c = t & 15;
  if (node >= NODES) return;
  float acc = x[node * INF_ + c];
  int r1 = rowptr[node + 1];
  for (int idx = rowptr[node]; idx < r1; ++idx) {
    int j = col[idx];
    acc += x[j * INF_ + c];
  }
  h0[node * INF_ + c] = acc;
}

// ---- z1 = relu(h0 @ W1a + b1a), K=16 ----
__global__ void k_gemm_k16(const float* __restrict__ h0, const float* __restrict__ W,
                           const float* __restrict__ bias, float* __restrict__ out) {
  int r = blockIdx.y;
  int c = blockIdx.x * 256 + threadIdx.x;
  float acc = bias[c];
#pragma unroll
  for (int k = 0; k < INF_; ++k)
    acc = fmaf(h0[r * INF_ + k], W[k * DD + c], acc);
  out[r * DD + c] = fmaxf(acc, 0.f);
}

// ---- aggregation on [NODES,512] fp32 (gather over CSR, no atomics) ----
__global__ __launch_bounds__(128) void k_agg512(const float* __restrict__ h, const int* __restrict__ rowptr,
                                                const int* __restrict__ col, float* __restrict__ out) {
  int node = blockIdx.x;
  int c4 = threadIdx.x * 4;
  const float4* hv = (const float4*)h;
  float4 acc = hv[(node * DD + c4) >> 2];
  int r0 = rowptr[node], r1 = rowptr[node + 1];
  for (int idx = r0; idx < r1; ++idx) {
    int j = col[idx];
    float4 v = hv[(j * DD + c4) >> 2];
    acc.x += v.x; acc.y += v.y; acc.z += v.z; acc.w += v.w;
  }
  ((float4*)out)[(node * DD + c4) >> 2] = acc;
}

// ---- fp32 SGEMM: C[M,512] = act(A[M,512] @ W[512,512] + bias) ----
// 64x64 tile, 256 threads, 4x4 per thread, BK=16 LDS staging
template <int RELU>
__global__ __launch_bounds__(256) void sgemm_bias_act(
    const float* __restrict__ A, const float* __restrict__ W,
    const float* __restrict__ bias, float* __restrict__ C, int M) {
  __shared__ float As[16][68];
  __shared__ float Ws[16][64];
  const int t = threadIdx.x;
  const int bm = blockIdx.y * 64;
  const int bn = blockIdx.x * 64;
  const int tx = t & 15, ty = t >> 4;
  const int ar = t >> 2;           // 0..63 (A row within tile)
  const int ak = (t & 3) * 4;      // 0,4,8,12 (A k within tile)
  const int wk = t >> 4;           // 0..15
  const int wn = (t & 15) * 4;     // 0..60
  const int arow = bm + ar;
  float acc[4][4] = {};
  for (int k0 = 0; k0 < 512; k0 += 16) {
    float4 av = make_float4(0.f, 0.f, 0.f, 0.f);
    if (arow < M) av = *(const float4*)(A + arow * 512 + k0 + ak);
    float4 wv = *(const float4*)(W + (k0 + wk) * 512 + bn + wn);
    As[ak + 0][ar] = av.x; As[ak + 1][ar] = av.y; As[ak + 2][ar] = av.z; As[ak + 3][ar] = av.w;
    *(float4*)&Ws[wk][wn] = wv;
    __syncthreads();
#pragma unroll
    for (int kk = 0; kk < 16; ++kk) {
      float4 a = *(const float4*)&As[kk][ty * 4];
      float4 b = *(const float4*)&Ws[kk][tx * 4];
      float aa[4] = {a.x, a.y, a.z, a.w};
      float bbv[4] = {b.x, b.y, b.z, b.w};
#pragma unroll
      for (int i = 0; i < 4; ++i)
#pragma unroll
        for (int j = 0; j < 4; ++j)
          acc[i][j] = fmaf(aa[i], bbv[j], acc[i][j]);
    }
    __syncthreads();
  }
  float bv[4];
#pragma unroll
  for (int j = 0; j < 4; ++j) bv[j] = bias[bn + tx * 4 + j];
#pragma unroll
  for (int i = 0; i < 4; ++i) {
    int row = bm + ty * 4 + i;
    if (row < M) {
      float o0 = acc[i][0] + bv[0], o1 = acc[i][1] + bv[1];
      float o2 = acc[i][2] + bv[2], o3 = acc[i][3] + bv[3];
      if (RELU) { o0 = fmaxf(o0, 0.f); o1 = fmaxf(o1, 0.f); o2 = fmaxf(o2, 0.f); o3 = fmaxf(o3, 0.f); }
      *(float4*)(C + row * 512 + bn + tx * 4) = make_float4(o0, o1, o2, o3);
    }
  }
}

// ---- BatchNorm: stats (sum,sumsq per channel), finalize (scale,shift), apply ----
__global__ __launch_bounds__(256) void k_bn_stats(const float* __restrict__ h, float* __restrict__ sums) {
  int t = threadIdx.x;
  int c2 = t * 2;
  int r0 = blockIdx.x * 40;
  float sx = 0.f, sy = 0.f, qx = 0.f, qy = 0.f;
  for (int r = r0; r < r0 + 40; ++r) {
    float2 v = *(const float2*)(h + r * DD + c2);
    sx += v.x; sy += v.y; qx += v.x * v.x; qy += v.y * v.y;
  }
  atomicAdd(&sums[c2], sx); atomicAdd(&sums[c2 + 1], sy);
  atomicAdd(&sums[DD + c2], qx); atomicAdd(&sums[DD + c2 + 1], qy);
}

__global__ void k_bn_finalize(const float* __restrict__ sums, const float* __restrict__ gamma,
                              const float* __restrict__ beta, float* __restrict__ ss) {
  int c = threadIdx.x;  // block 512
  float mean = sums[c] * (1.f / NODES);
  float var = sums[DD + c] * (1.f / NODES) - mean * mean;
  float sc = gamma[c] * rsqrtf(var + BN_EPS);
  ss[c] = sc;
  ss[DD + c] = beta[c] - mean * sc;
}

__global__ void k_bn_apply(float* __restrict__ h, const float* __restrict__ ss) {
  int i = blockIdx.x * 256 + threadIdx.x;  // float4 index
  int c4 = (i & 127) * 4;
  float4 v = ((float4*)h)[i];
  v.x = v.x * ss[c4 + 0] + ss[DD + c4 + 0];
  v.y = v.y * ss[c4 + 1] + ss[DD + c4 + 1];
  v.z = v.z * ss[c4 + 2] + ss[DD + c4 + 2];
  v.w = v.w * ss[c4 + 3] + ss[DD + c4 + 3];
  ((float4*)h)[i] = v;
}

// ---- pooling ----
__global__ void k_pool_cnt(const int* __restrict__ batch, float* __restrict__ gcnt) {
  int r = blockIdx.x * 256 + threadIdx.x;
  if (r < NODES) atomicAdd(&gcnt[batch[r]], 1.f);
}

__global__ __launch_bounds__(128) void k_pool_sum(const float* __restrict__ h, const int* __restrict__ batch,
                                                  float* __restrict__ gsum) {
  int c4 = threadIdx.x * 4;
  int r0 = blockIdx.x * 100;
  int r1 = min(r0 + 100, NODES);
  if (r0 >= r1) return;
  float4 acc = make_float4(0.f, 0.f, 0.f, 0.f);
  int gcur = batch[r0];
  for (int r = r0; r < r1; ++r) {
    int g = batch[r];
    if (g != gcur) {
      atomicAdd(&gsum[gcur * DD + c4 + 0], acc.x);
      atomicAdd(&gsum[gcur * DD + c4 + 1], acc.y);
      atomicAdd(&gsum[gcur * DD + c4 + 2], acc.z);
      atomicAdd(&gsum[gcur * DD + c4 + 3], acc.w);
      acc = make_float4(0.f, 0.f, 0.f, 0.f);
      gcur = g;
    }
    float4 v = *(const float4*)(h + r * DD + c4);
    acc.x += v.x; acc.y += v.y; acc.z += v.z; acc.w += v.w;
  }
  atomicAdd(&gsum[gcur * DD + c4 + 0], acc.x);
  atomicAdd(&gsum[gcur * DD + c4 + 1], acc.y);
  atomicAdd(&gsum[gcur * DD + c4 + 2], acc.z);
  atomicAdd(&gsum[gcur * DD + c4 + 3], acc.w);
}

// ---- head: feats = tanh(pooled @ Wfc + bfc) ----
__global__ __launch_bounds__(512) void k_head(const float* __restrict__ gsum, const float* __restrict__ gcnt,
                                              const float* __restrict__ Wfc, const float* __restrict__ bfc,
                                              float* __restrict__ feats) {
  int g = blockIdx.x, c = threadIdx.x;
  float inv = 1.f / fmaxf(gcnt[g], 1.f);
  float acc = bfc[c];
  const float* row = gsum + g * DD;
  for (int k = 0; k < DD; ++k)
    acc = fmaf(row[k] * inv, Wfc[k * DD + c], acc);
  feats[g * DD + c] = tanhf(acc);
}

// ---- logits = feats @ Wlog + blog, out fp32 ----
__global__ void k_logits(const float* __restrict__ feats, const float* __restrict__ Wlog,
                         const float* __restrict__ blog, float* __restrict__ out) {
  int g = blockIdx.x, o = threadIdx.x;
  if (o >= NOUT) return;
  float acc = blog[o];
  const float* f = feats + g * DD;
  for (int k = 0; k < DD; ++k)
    acc = fmaf(f[k], Wlog[k * NOUT + o], acc);
  out[g * NOUT + o] = acc;
}

extern "C" void kernel_launch(void* const* d_in, const int* in_sizes, int n_in,
                              void* d_out, int out_size, void* d_ws, size_t ws_size,
                              hipStream_t stream) {
  const float* x = (const float*)d_in[0];
  const int* ei = (const int*)d_in[1];
  const int* batch = (const int*)d_in[2];
  const float* W1a = (const float*)d_in[3];
  const float* b1a = (const float*)d_in[4];
  const float* W1b = (const float*)d_in[5];
  const float* b1b = (const float*)d_in[6];
  const float* Wa = (const float*)d_in[7];
  const float* ba = (const float*)d_in[8];
  const float* Wb = (const float*)d_in[9];
  const float* bb = (const float*)d_in[10];
  const float* bng = (const float*)d_in[11];
  const float* bnb = (const float*)d_in[12];
  const float* Wfc = (const float*)d_in[13];
  const float* bfc = (const float*)d_in[14];
  const float* Wlog = (const float*)d_in[15];
  const float* blog = (const float*)d_in[16];
  float* out = (float*)d_out;

  const int* src = ei;
  const int* dstp = ei + EDGES;

  char* w = (char*)d_ws;
  int* rowptr = (int*)(w);                 // 10001 ints
  int* cur    = (int*)(w + 40192);         // 10000 ints
  int* col    = (int*)(w + 80384);         // 160000 ints
  float* h0   = (float*)(w + 720384);      // 160000 f
  float* bnsums = (float*)(w + 1360384);   // 1024 f (sum | sumsq)
  float* bnss   = (float*)(w + 1364480);   // 1024 f (scale | shift)
  float* gsum   = (float*)(w + 1368576);   // 32768 f
  float* gcnt   = (float*)(w + 1499648);   // 64 f   (contiguous after gsum)
  float* feats  = (float*)(w + 1499904);   // 32768 f
  float* bufA   = (float*)(w + 1630976);   // 5,120,000 f
  float* bufB   = (float*)(w + 22110976);  // 5,120,000 f  (end ~42.6 MB)

  // CSR build
  k_zero_i32<<<40, 256, 0, stream>>>(cur, NODES);
  k_count<<<625, 256, 0, stream>>>(dstp, cur);
  k_scan<<<1, 1024, 0, stream>>>(cur, rowptr);
  k_zero_i32<<<40, 256, 0, stream>>>(cur, NODES);
  k_fill<<<625, 256, 0, stream>>>(src, dstp, rowptr, cur, col);

  // layer 1
  k_agg16<<<625, 256, 0, stream>>>(x, rowptr, col, h0);
  k_gemm_k16<<<dim3(2, NODES), 256, 0, stream>>>(h0, W1a, b1a, bufA);
  sgemm_bias_act<1><<<dim3(8, 157), 256, 0, stream>>>(bufA, W1b, b1b, bufB, NODES);
  k_zero_f32<<<4, 256, 0, stream>>>(bnsums, 1024);
  k_bn_stats<<<250, 256, 0, stream>>>(bufB, bnsums);
  k_bn_finalize<<<1, 512, 0, stream>>>(bnsums, bng, bnb, bnss);
  k_bn_apply<<<5000, 256, 0, stream>>>(bufB, bnss);

  // layers 2..5 (ping-pong H/T)
  float* H = bufB;
  float* T = bufA;
  for (int i = 0; i < 4; ++i) {
    k_agg512<<<NODES, 128, 0, stream>>>(H, rowptr, col, T);
    sgemm_bias_act<1><<<dim3(8, 157), 256, 0, stream>>>(T, Wa + i * DD * DD, ba + i * DD, H, NODES);
    sgemm_bias_act<1><<<dim3(8, 157), 256, 0, stream>>>(H, Wb + i * DD * DD, bb + i * DD, T, NODES);
    k_zero_f32<<<4, 256, 0, stream>>>(bnsums, 1024);
    k_bn_stats<<<250, 256, 0, stream>>>(T, bnsums);
    k_bn_finalize<<<1, 512, 0, stream>>>(bnsums, bng + (i + 1) * DD, bnb + (i + 1) * DD, bnss);
    k_bn_apply<<<5000, 256, 0, stream>>>(T, bnss);
    float* tmp = H; H = T; T = tmp;
  }

  // pooling + head
  k_zero_f32<<<129, 256, 0, stream>>>(gsum, GRAPHS * DD + GRAPHS);  // gsum + gcnt contiguous
  k_pool_cnt<<<40, 256, 0, stream>>>(batch, gcnt);
  k_pool_sum<<<100, 128, 0, stream>>>(H, batch, gsum);
  k_head<<<GRAPHS, 512, 0, stream>>>(gsum, gcnt, Wfc, bfc, feats);
  k_logits<<<GRAPHS, 64, 0, stream>>>(feats, Wlog, blog, out);
}